// Round 9
// baseline (32024.533 us; speedup 1.0000x reference)
//
#include <hip/hip_runtime.h>
#include <hip/hip_bf16.h>

typedef __hip_bfloat16 bf16;
typedef __attribute__((ext_vector_type(8))) short short8;
typedef __attribute__((ext_vector_type(4))) float floatx4;

#define TM 64
#define TN 64
#define TK 16
#define LDP 68

__device__ __forceinline__ float ldE(const float* p) { return *p; }
__device__ __forceinline__ float ldE(const bf16* p)  { return (float)*p; }
__device__ __forceinline__ void stC(float* p, float v) { *p = v; }
__device__ __forceinline__ void stC(bf16* p, float v)  { *p = __float2bfloat16(v); }

__device__ __forceinline__ float sigm(float x) {
    x = fminf(fmaxf(x, -40.f), 40.f);
    return 1.f / (1.f + expf(-x));
}
__device__ __forceinline__ float tanh_s(float x) {
    x = fminf(fmaxf(x, -20.f), 20.f);
    float e = expf(2.f * x);
    return 1.f - 2.f / (e + 1.f);
}

// ---------------- fp32 batched GEMM (word phase only) ----------------
template <typename AT, typename WT, typename CT>
__global__ __launch_bounds__(256) void gemm_aw(
    const AT* __restrict__ A, long sAd,
    const WT* __restrict__ W, long sWd,
    CT* __restrict__ C, long sCd,
    int M, int Nc, int K)
{
    __shared__ alignas(16) float As[TK][LDP];
    __shared__ alignas(16) float Ws[TK][LDP];
    const int d = blockIdx.z;
    A += (long)d * sAd; W += (long)d * sWd; C += (long)d * sCd;
    const int m0 = blockIdx.y * TM;
    const int n0 = blockIdx.x * TN;
    const int tid = threadIdx.x;
    const int tx = tid & 15, ty = tid >> 4;

    float acc[4][4] = {};
    for (int k0 = 0; k0 < K; k0 += TK) {
#pragma unroll
        for (int i = 0; i < 4; ++i) {
            int e = tid + i * 256;
            int m = e >> 4;
            int kk = e & 15;
            float va = 0.f, vw = 0.f;
            if (m0 + m < M && k0 + kk < K) va = ldE(&A[(long)(m0 + m) * K + k0 + kk]);
            if (n0 + m < Nc && k0 + kk < K) vw = ldE(&W[(long)(n0 + m) * K + k0 + kk]);
            As[kk][m] = va;
            Ws[kk][m] = vw;
        }
        __syncthreads();
#pragma unroll
        for (int kk = 0; kk < TK; ++kk) {
            float4 a4 = *reinterpret_cast<const float4*>(&As[kk][ty * 4]);
            float4 b4 = *reinterpret_cast<const float4*>(&Ws[kk][tx * 4]);
            float a[4] = {a4.x, a4.y, a4.z, a4.w};
            float b[4] = {b4.x, b4.y, b4.z, b4.w};
#pragma unroll
            for (int i = 0; i < 4; ++i)
#pragma unroll
                for (int j = 0; j < 4; ++j)
                    acc[i][j] += a[i] * b[j];
        }
        __syncthreads();
    }
#pragma unroll
    for (int i = 0; i < 4; ++i) {
        int m = m0 + ty * 4 + i;
        if (m >= M) continue;
#pragma unroll
        for (int j = 0; j < 4; ++j) {
            int n = n0 + tx * 4 + j;
            if (n < Nc) stC(&C[(long)m * Nc + n], acc[i][j]);
        }
    }
}

// ---- convert f32 weight [2, G, K] -> padded bf16 [2, 2176, KP] (zeros pad) ----
__global__ void wpad_cvt(const float* __restrict__ W, bf16* __restrict__ out,
                         int G, int K, int KP)
{
    long idx = (long)blockIdx.x * 256 + threadIdx.x;
    long tot = 2ll * 2176 * KP;
    if (idx >= tot) return;
    int k = idx % KP;
    int r = (idx / KP) % 2176;
    int d = idx / ((long)KP * 2176);
    float v = (r < G && k < K) ? W[((long)d * G + r) * K + k] : 0.f;
    out[idx] = __float2bfloat16(v);
}

// ---- MFMA bf16 GEMM: C[d] = A[d] (M x KP bf16) @ Wp[d]^T (2176 x KP bf16) ----
// 128x128 tile, 4 waves in 2x2, each wave 4x4 16x16x32 MFMA tiles (m97 pattern).
// M % 128 == 0; KP % 32 == 0. C row stride ldc, cols guarded < Nc.
__global__ __launch_bounds__(256) void gemm_mfma(
    const bf16* __restrict__ A, long sAd, int KP,
    const bf16* __restrict__ Wp,            // [2, 2176, KP]
    bf16* __restrict__ C, long sCd, int Nc, int ldc)
{
    __shared__ short As[128 * 32];
    __shared__ short Ws[128 * 32];
    const int d = blockIdx.z;
    const short* Ag = (const short*)(A + (long)d * sAd);
    const short* Wg = (const short*)(Wp + (long)d * 2176 * KP);
    const int n0 = blockIdx.x * 128;
    const int m0 = blockIdx.y * 128;
    const int tid  = threadIdx.x;
    const int wave = tid >> 6;
    const int lane = tid & 63;
    const int l15  = lane & 15;
    const int quad = lane >> 4;
    const int wm = (wave >> 1) * 64;
    const int wn = (wave & 1) * 64;

    floatx4 acc[4][4];
#pragma unroll
    for (int i = 0; i < 4; ++i)
#pragma unroll
        for (int j = 0; j < 4; ++j)
            acc[i][j] = (floatx4){0.f, 0.f, 0.f, 0.f};

    for (int k0 = 0; k0 < KP; k0 += 32) {
#pragma unroll
        for (int r = 0; r < 2; ++r) {
            int c = tid + r * 256;          // 0..511 16B-chunks
            int row = c >> 2;
            int ko  = (c & 3) * 8;
            *(int4*)&As[row * 32 + ko] = *(const int4*)&Ag[(long)(m0 + row) * KP + k0 + ko];
            *(int4*)&Ws[row * 32 + ko] = *(const int4*)&Wg[(long)(n0 + row) * KP + k0 + ko];
        }
        __syncthreads();
        short8 af[4], bf[4];
#pragma unroll
        for (int i = 0; i < 4; ++i) {
            af[i] = *(const short8*)&As[(wm + i * 16 + l15) * 32 + quad * 8];
            bf[i] = *(const short8*)&Ws[(wn + i * 16 + l15) * 32 + quad * 8];
        }
#pragma unroll
        for (int i = 0; i < 4; ++i)
#pragma unroll
            for (int j = 0; j < 4; ++j)
                acc[i][j] = __builtin_amdgcn_mfma_f32_16x16x32_bf16(af[i], bf[j], acc[i][j], 0, 0, 0);
        __syncthreads();
    }

    bf16* Cd = C + (long)d * sCd;
#pragma unroll
    for (int i = 0; i < 4; ++i) {
#pragma unroll
        for (int j = 0; j < 4; ++j) {
            int col = n0 + wn + j * 16 + l15;
            if (col >= Nc) continue;
            int rowb = m0 + wm + i * 16 + quad * 4;
#pragma unroll
            for (int r = 0; r < 4; ++r)
                Cd[(long)(rowb + r) * ldc + col] = __float2bfloat16(acc[i][j][r]);
        }
    }
}

// ---- fused sentence step: gh GEMM (coalesced, LDS-tiled) + gates + h update ----
// Grid (22 j-tiles, 4 m-tiles, 2 dirs) x 256 threads. Tile: 32 batch x 32 j x 3 gates.
#define SCH 60
__global__ __launch_bounds__(256) void step_sent(
    const float* __restrict__ Whh,   // [2, 2100, 700] f32
    const float* __restrict__ bih,   // [2, 2100]
    const float* __restrict__ bhh,   // [2, 2100]
    const bf16*  __restrict__ xw,    // [2, SCH, 128, 2100] bf16
    const float* __restrict__ hR,    // [2, 128, 700]
    float*       __restrict__ hW,    // [2, 128, 700]
    bf16*        __restrict__ y,     // [120, 128, 1408] or nullptr
    int kg, int tb0, int tb1)
{
    const int H = 700, G = 2100, B = 128;
    const int d  = blockIdx.z;
    const int m0 = blockIdx.y * 32;
    const int j0 = blockIdx.x * 32;
    const int tid = threadIdx.x;
    const int tx = tid & 15, ty = tid >> 4;

    __shared__ alignas(16) float Ah[32][34];
    __shared__ alignas(16) float Wl[3][32][34];

    const int t_eff = (d == 0) ? kg : (119 - kg);
    const int t_loc = t_eff - ((d == 0) ? tb0 : tb1);
    const float* hr = hR + (long)d * B * H;
    float*       hw = hW + (long)d * B * H;

    float acc[2][2][3] = {};
    for (int k0 = 0; k0 < H; k0 += 32) {
#pragma unroll
        for (int i = 0; i < 4; ++i) {
            int e = tid + i * 256;
            int m = e >> 5, kk = e & 31;
            Ah[kk][m] = (k0 + kk < H) ? hr[(long)(m0 + m) * H + k0 + kk] : 0.f;
        }
#pragma unroll
        for (int g = 0; g < 3; ++g)
#pragma unroll
            for (int i = 0; i < 4; ++i) {
                int e = tid + i * 256;
                int j = e >> 5, kk = e & 31;
                float v = 0.f;
                if (j0 + j < H && k0 + kk < H)
                    v = Whh[((long)d * G + g * H + j0 + j) * H + k0 + kk];
                Wl[g][kk][j] = v;
            }
        __syncthreads();
#pragma unroll
        for (int kk = 0; kk < 32; ++kk) {
            float2 a2 = *(const float2*)&Ah[kk][ty * 2];
            float2 w0 = *(const float2*)&Wl[0][kk][tx * 2];
            float2 w1 = *(const float2*)&Wl[1][kk][tx * 2];
            float2 w2 = *(const float2*)&Wl[2][kk][tx * 2];
            acc[0][0][0] += a2.x * w0.x;  acc[0][1][0] += a2.x * w0.y;
            acc[1][0][0] += a2.y * w0.x;  acc[1][1][0] += a2.y * w0.y;
            acc[0][0][1] += a2.x * w1.x;  acc[0][1][1] += a2.x * w1.y;
            acc[1][0][1] += a2.y * w1.x;  acc[1][1][1] += a2.y * w1.y;
            acc[0][0][2] += a2.x * w2.x;  acc[0][1][2] += a2.x * w2.y;
            acc[1][0][2] += a2.y * w2.x;  acc[1][1][2] += a2.y * w2.y;
        }
        __syncthreads();
    }

    const bf16* xwb = xw + ((long)d * SCH + t_loc) * B * (long)G;
#pragma unroll
    for (int mi = 0; mi < 2; ++mi) {
        int m = m0 + ty * 2 + mi;
#pragma unroll
        for (int ji = 0; ji < 2; ++ji) {
            int j = j0 + tx * 2 + ji;
            if (j >= H) continue;
            float br = bih[(long)d * G + j];
            float bz = bih[(long)d * G + H + j];
            float bn = bih[(long)d * G + 2 * H + j];
            float pr = bhh[(long)d * G + j];
            float pz = bhh[(long)d * G + H + j];
            float pn = bhh[(long)d * G + 2 * H + j];
            const bf16* xp = xwb + (long)m * G;
            float xr = (float)xp[j]         + br;
            float xz = (float)xp[H + j]     + bz;
            float xn = (float)xp[2 * H + j] + bn;
            float r  = sigm(xr + acc[mi][ji][0] + pr);
            float z  = sigm(xz + acc[mi][ji][1] + pz);
            float nn = tanh_s(xn + r * (acc[mi][ji][2] + pn));
            float hold = hr[(long)m * H + j];
            float hnew = (1.f - z) * nn + z * hold;
            hw[(long)m * H + j] = hnew;
            if (y) y[((long)t_eff * B + m) * 1408 + d * 700 + j] = __float2bfloat16(hnew);
        }
    }
}

// ---- word layer-0 GRU step (embW gather) ----
__global__ void gru_step_word0(
    const int* __restrict__ x, const bf16* __restrict__ embW,
    const float* __restrict__ gh, const float* __restrict__ bih,
    const float* __restrict__ bhh, float* __restrict__ h,
    bf16* __restrict__ y, int S, int T, int B, int V, int H, int k)
{
    const int N = S * B;
    long idx = (long)blockIdx.x * 256 + threadIdx.x;
    if (idx >= 2ll * N * H) return;
    int j = idx % H;
    int n = (idx / H) % N;
    int d = idx / ((long)N * H);
    int G = 3 * H;
    int t_eff = (d == 0) ? k : (T - 1 - k);
    int s = n / B, b = n % B;
    int tok = x[((long)s * T + t_eff) * B + b];
    tok = max(0, min(V - 1, tok));

    const bf16*  xp = embW + ((long)d * V + tok) * G;
    const float* gp = gh + ((long)d * N + n) * G;
    const float* bi = bih + (long)d * G;
    const float* bh = bhh + (long)d * G;

    float xr = (float)xp[j]         + bi[j];
    float xz = (float)xp[H + j]     + bi[H + j];
    float xn = (float)xp[2 * H + j] + bi[2 * H + j];
    float hr = gp[j]         + bh[j];
    float hz = gp[H + j]     + bh[H + j];
    float hn = gp[2 * H + j] + bh[2 * H + j];

    float r = sigm(xr + hr);
    float z = sigm(xz + hz);
    float nn = tanh_s(xn + r * hn);

    long hidx = ((long)d * N + n) * H + j;
    float hnew = (1.f - z) * nn + z * h[hidx];
    h[hidx] = hnew;
    y[((long)t_eff * N + n) * (2 * H) + (long)d * H + j] = __float2bfloat16(hnew);
}

// ---- generic GRU step (word layer 1) ----
__global__ void gru_step1(
    const bf16* __restrict__ xw, int tb0, int tb1, int Cbuf,
    const float* __restrict__ gh, const float* __restrict__ bih,
    const float* __restrict__ bhh, float* __restrict__ h,
    bf16* __restrict__ y, int N, int H, int L, int k)
{
    long idx = (long)blockIdx.x * 256 + threadIdx.x;
    if (idx >= 2ll * N * H) return;
    int j = idx % H;
    int n = (idx / H) % N;
    int d = idx / ((long)N * H);
    int G = 3 * H;
    int t_eff = (d == 0) ? k : (L - 1 - k);
    int t_local = t_eff - ((d == 0) ? tb0 : tb1);

    const bf16*  xp = xw + (((long)d * Cbuf + t_local) * N + n) * G;
    const float* gp = gh + ((long)d * N + n) * G;
    const float* bi = bih + (long)d * G;
    const float* bh = bhh + (long)d * G;

    float xr = (float)xp[j]         + bi[j];
    float xz = (float)xp[H + j]     + bi[H + j];
    float xn = (float)xp[2 * H + j] + bi[2 * H + j];
    float hr = gp[j]         + bh[j];
    float hz = gp[H + j]     + bh[H + j];
    float hn = gp[2 * H + j] + bh[2 * H + j];

    float r = sigm(xr + hr);
    float z = sigm(xz + hz);
    float nn = tanh_s(xn + r * hn);

    long hidx = ((long)d * N + n) * H + j;
    float hnew = (1.f - z) * nn + z * h[hidx];
    h[hidx] = hnew;
    if (y) y[((long)t_eff * N + n) * (2 * H) + (long)d * H + j] = __float2bfloat16(hnew);
}

// out[n, ostride] cols [ha_d0 | ha_d1 | hb_d0 | hb_d1]
template <typename OT>
__global__ void concat4(const float* __restrict__ ha, const float* __restrict__ hb,
                        OT* __restrict__ out, int N, int H, int ostride)
{
    long idx = (long)blockIdx.x * 256 + threadIdx.x;
    int C4 = 4 * H;
    if (idx >= (long)N * C4) return;
    int c = idx % C4;
    long n = idx / C4;
    int blk = c / H, j = c % H;
    const float* src = (blk < 2) ? ha : hb;
    int dd = blk & 1;
    stC(&out[n * (long)ostride + c], src[((long)dd * N + n) * H + j]);
}

extern "C" void kernel_launch(void* const* d_in, const int* in_sizes, int n_in,
                              void* d_out, int out_size, void* d_ws, size_t ws_size,
                              hipStream_t stream)
{
    const int S = 120, T = 10, B = 128, E = 80, HW = 75, HS = 700, V = 30000;
    const int Nw = S * B;            // 15360
    const int Gw = 3 * HW;           // 225
    const int Gs = 3 * HS;           // 2100
    const int CH = SCH;              // 60
    const int KP0 = 320, KP1 = 1408; // padded K for MFMA chunk GEMMs
    (void)in_sizes; (void)n_in; (void)out_size; (void)ws_size;

    const int*   x       = (const int*)d_in[0];
    const float* emb     = (const float*)d_in[1];
    const float* we_Wih0 = (const float*)d_in[2],  *we_Whh0 = (const float*)d_in[3];
    const float* we_bih0 = (const float*)d_in[4],  *we_bhh0 = (const float*)d_in[5];
    const float* we_Wih1 = (const float*)d_in[6],  *we_Whh1 = (const float*)d_in[7];
    const float* we_bih1 = (const float*)d_in[8],  *we_bhh1 = (const float*)d_in[9];
    const float* se_Wih0 = (const float*)d_in[10], *se_Whh0 = (const float*)d_in[11];
    const float* se_bih0 = (const float*)d_in[12], *se_bhh0 = (const float*)d_in[13];
    const float* se_Wih1 = (const float*)d_in[14], *se_Whh1 = (const float*)d_in[15];
    const float* se_bih1 = (const float*)d_in[16], *se_bhh1 = (const float*)d_in[17];

    // ---- arenas (145.9 MB total; < proven-safe 149 MB) ----
    char* ws = (char*)d_ws;
    const size_t szA = 9830400;    // words bf16 [15360, 320]  (K-padded)
    const size_t szB = 46080000;   // y0w bf16 [T*Nw,150] -> y0s bf16 [15360, 1408]
    const size_t szC = 68472000;   // word: embW 27.0 | gh_w 27.648 | xw_w1 13.824
                                   // sent: xw_ch bf16 [2,60,128,2100] = 64.512
    const size_t szF = 12300000;   // word: h_w0 (9.216) ; sent: Wp1 bf16 [2,2176,1408]=12.255
    const size_t szG = 9216000;    // word: h_w1 ; sent: h bufs (2.867) + Wp0 (2.785)
    char* pA = ws;
    char* pB = pA + szA;
    char* pC = pB + szB;
    char* pF = pC + szC;
    char* pG = pF + szF;
    const size_t total = szA + szB + szC + szF + szG;   // 145,898,400

    bf16*  words  = (bf16*)pA;
    bf16*  y0w    = (bf16*)pB;
    bf16*  y0s    = (bf16*)pB;
    bf16*  embW   = (bf16*)pC;
    float* gh_w   = (float*)(pC + 27000000);
    bf16*  xw_w1  = (bf16*)(pC + 27000000 + 27648000);
    bf16*  xw_ch  = (bf16*)pC;                         // sentence overlay
    float* h_w0   = (float*)pF;
    bf16*  Wp1    = (bf16*)pF;                         // sentence overlay
    float* h_w1   = (float*)pG;
    float* hs0a = (float*)pG;                          // sentence overlays
    float* hs0b = (float*)(pG + 716800);
    float* hs1a = (float*)(pG + 1433600);
    float* hs1b = (float*)(pG + 2150400);
    bf16*  Wp0  = (bf16*)(pG + 4000000);               // 2,785,280 B

    hipMemsetAsync(ws, 0, total, stream);  // poison kill + h0 + all pad zeros

    auto grid = [](int M, int Nc) {
        return dim3((Nc + TN - 1) / TN, (M + TM - 1) / TM, 2);
    };

    // ===================== word encoder (fp32 path, unchanged) ==============
    gemm_aw<float, float, bf16><<<grid(V, Gw), 256, 0, stream>>>(
        emb, 0, we_Wih0, (long)Gw * E, embW, (long)V * Gw, V, Gw, E);
    for (int k = 0; k < T; ++k) {
        gemm_aw<float, float, float><<<grid(Nw, Gw), 256, 0, stream>>>(
            h_w0, (long)Nw * HW, we_Whh0, (long)Gw * HW, gh_w, (long)Nw * Gw, Nw, Gw, HW);
        long tot = 2ll * Nw * HW;
        gru_step_word0<<<(tot + 255) / 256, 256, 0, stream>>>(
            x, embW, gh_w, we_bih0, we_bhh0, h_w0, y0w, S, T, B, V, HW, k);
    }
    for (int k = 0; k < T; ++k) {
        gemm_aw<bf16, float, bf16><<<grid(Nw, Gw), 256, 0, stream>>>(
            y0w + (long)k * Nw * 2 * HW, (long)(T - 1 - 2 * k) * Nw * 2 * HW,
            we_Wih1, (long)Gw * (2 * HW), xw_w1, (long)Nw * Gw, Nw, Gw, 2 * HW);
        gemm_aw<float, float, float><<<grid(Nw, Gw), 256, 0, stream>>>(
            h_w1, (long)Nw * HW, we_Whh1, (long)Gw * HW, gh_w, (long)Nw * Gw, Nw, Gw, HW);
        long tot = 2ll * Nw * HW;
        gru_step1<<<(tot + 255) / 256, 256, 0, stream>>>(
            xw_w1, k, T - 1 - k, 1, gh_w, we_bih1, we_bhh1, h_w1, nullptr, Nw, HW, T, k);
    }
    {   // words: K-padded stride 320 (pad cols stay 0 from the big memset)
        long tot = (long)Nw * 4 * HW;
        concat4<bf16><<<(tot + 255) / 256, 256, 0, stream>>>(h_w0, h_w1, words, Nw, HW, KP0);
    }

    // ===================== sentence encoder =====================
    // Clear arena B (kills stale y0w before y0s pad cols matter) + h bufs/Wp0 area.
    hipMemsetAsync(pB, 0, szB, stream);
    hipMemsetAsync(pG, 0, 7000000, stream);
    // Convert weights to padded bf16.
    {
        long t0 = 2ll * 2176 * KP0;
        wpad_cvt<<<(t0 + 255) / 256, 256, 0, stream>>>(se_Wih0, Wp0, Gs, 4 * HW, KP0);
        long t1 = 2ll * 2176 * KP1;
        wpad_cvt<<<(t1 + 255) / 256, 256, 0, stream>>>(se_Wih1, Wp1, Gs, 2 * HS, KP1);
    }

    const dim3 mg(17, 60, 2);         // N-tiles x M-tiles x dirs (M = 60*128 = 7680)
    const dim3 sgrid(22, 4, 2);       // j-tiles x batch-tiles x dirs

    // ---- layer 0 ----
    for (int c = 0; c < 2; ++c) {
        int tb0 = c * CH, tb1 = S - c * CH - CH;
        gemm_mfma<<<mg, 256, 0, stream>>>(
            words + (long)tb0 * B * KP0, (long)(tb1 - tb0) * B * KP0, KP0,
            Wp0, xw_ch, (long)CH * B * Gs, Gs, Gs);
        for (int k = c * CH; k < c * CH + CH; ++k) {
            const float* hRb = (k & 1) ? hs0b : hs0a;
            float*       hWb = (k & 1) ? hs0a : hs0b;
            step_sent<<<sgrid, 256, 0, stream>>>(
                se_Whh0, se_bih0, se_bhh0, xw_ch, hRb, hWb, y0s, k, tb0, tb1);
        }
    }
    // ---- layer 1 ----
    for (int c = 0; c < 2; ++c) {
        int tb0 = c * CH, tb1 = S - c * CH - CH;
        gemm_mfma<<<mg, 256, 0, stream>>>(
            y0s + (long)tb0 * B * KP1, (long)(tb1 - tb0) * B * KP1, KP1,
            Wp1, xw_ch, (long)CH * B * Gs, Gs, Gs);
        for (int k = c * CH; k < c * CH + CH; ++k) {
            const float* hRb = (k & 1) ? hs1b : hs1a;
            float*       hWb = (k & 1) ? hs1a : hs1b;
            step_sent<<<sgrid, 256, 0, stream>>>(
                se_Whh1, se_bih1, se_bhh1, xw_ch, hRb, hWb, nullptr, k, tb0, tb1);
        }
    }

    // out[1, B, 4*HS] (float32); 120 steps -> final state in the 'a' buffers.
    {
        long tot = (long)B * 4 * HS;
        concat4<float><<<(tot + 255) / 256, 256, 0, stream>>>(
            hs0a, hs1a, (float*)d_out, B, HS, 4 * HS);
    }
}